// Round 8
// baseline (112.559 us; speedup 1.0000x reference)
//
#include <hip/hip_runtime.h>
#include <stdint.h>

#define V_CONST 50257
#define NMASK ((V_CONST + 31) / 32)
#define KTOP 50
#define CAND_CAP 1024
#define THR_SCREEN 13.0f
#define C_TEMP 1.25f
#define C_PEN ((float)(1.25 / 1.2))
#define Q4L 12564              // quarter length (mult of 4); last = 12565
#define THREEFRY_PARTITIONABLE 1

__device__ __forceinline__ void tf_round(uint32_t &x0, uint32_t &x1, int r) {
  x0 += x1;
  x1 = (x1 << r) | (x1 >> (32 - r));
  x1 ^= x0;
}

// Threefry-2x32, 20 rounds, key = (0, 42)  [jax.random.key(42)]
__device__ __forceinline__ uint2 threefry_k_0_42(uint32_t x0, uint32_t x1) {
  const uint32_t ks0 = 0u;
  const uint32_t ks1 = 42u;
  const uint32_t ks2 = 0x1BD11BDAu ^ 0u ^ 42u;
  x0 += ks0; x1 += ks1;
  tf_round(x0, x1, 13); tf_round(x0, x1, 15); tf_round(x0, x1, 26); tf_round(x0, x1, 6);
  x0 += ks1; x1 += ks2 + 1u;
  tf_round(x0, x1, 17); tf_round(x0, x1, 29); tf_round(x0, x1, 16); tf_round(x0, x1, 24);
  x0 += ks2; x1 += ks0 + 2u;
  tf_round(x0, x1, 13); tf_round(x0, x1, 15); tf_round(x0, x1, 26); tf_round(x0, x1, 6);
  x0 += ks0; x1 += ks1 + 3u;
  tf_round(x0, x1, 17); tf_round(x0, x1, 29); tf_round(x0, x1, 16); tf_round(x0, x1, 24);
  x0 += ks1; x1 += ks2 + 4u;
  tf_round(x0, x1, 13); tf_round(x0, x1, 15); tf_round(x0, x1, 26); tf_round(x0, x1, 6);
  x0 += ks2; x1 += ks0 + 5u;
  uint2 r; r.x = x0; r.y = x1; return r;
}

__device__ __forceinline__ float gumbel_at(uint32_t p, uint32_t half_total) {
  uint32_t bits;
#if THREEFRY_PARTITIONABLE
  uint2 o = threefry_k_0_42(0u, p);
  bits = o.x ^ o.y;
#else
  if (p < half_total) {
    uint2 o = threefry_k_0_42(p, p + half_total);
    bits = o.x;
  } else {
    uint2 o = threefry_k_0_42(p - half_total, p);
    bits = o.y;
  }
#endif
  uint32_t ub = (bits >> 9) | 0x3F800000u;
  float u = __uint_as_float(ub) - 1.0f;
  u = u + 1.17549435e-38f;
  u = fmaxf(1.17549435e-38f, u);
  return -logf(-logf(u));
}

__device__ __forceinline__ uint32_t f2u_desc(float f) {
  uint32_t b = __float_as_uint(f);
  return (b & 0x80000000u) ? ~b : (b | 0x80000000u);
}
__device__ __forceinline__ float u2f(uint32_t u) {
  uint32_t b = (u & 0x80000000u) ? (u & 0x7FFFFFFFu) : ~u;
  return __uint_as_float(b);
}

// ---- stable rank sort (descending, ties by smaller index) ----
template<int NT>
__device__ __forceinline__ void rank_sort(int n, uint32_t* cu, int* cidx,
                                          uint32_t* su, int* sidx, int tid) {
  for (int i = tid; i < n; i += NT) {
    uint32_t ui = cu[i]; int ii = cidx[i];
    int rank = 0;
    for (int j = 0; j < n; j++) {
      uint32_t uj = cu[j];
      rank += ((uj > ui) || (uj == ui && cidx[j] < ii)) ? 1 : 0;
    }
    su[rank] = ui; sidx[rank] = ii;
  }
}

// ---- bisection full-row rescan (robust fallback; never taken on this data) ----
template<int NT>
__device__ int rescan_bisect(const float* lrow, const uint32_t* mask,
                             int aoff, int body4, int tailn,
                             uint32_t* cu, int* cidx, uint32_t* su, int* sidx,
                             int* s_cnt, int tid) {
  const float4* arow4 = (const float4*)(lrow + aoff);
  float thr = THR_SCREEN;
  uint32_t ulo_ = 0u, uhi_ = 0xFFFFFFFFu;
  int n = 0;
  for (int attempt = 0; attempt < 64; ++attempt) {
    __syncthreads();
    if (tid == 0) *s_cnt = 0;
    __syncthreads();
    for (int t = tid; t < body4; t += NT) {
      float4 r = arow4[t];
      int v0 = aoff + (t << 2);
      uint32_t w = (mask[v0 >> 5] >> (v0 & 31)) & 0xFu;
      float m0 = (w & 1u) ? C_PEN : C_TEMP;
      float m1 = (w & 2u) ? C_PEN : C_TEMP;
      float m2 = (w & 4u) ? C_PEN : C_TEMP;
      float m3 = (w & 8u) ? C_PEN : C_TEMP;
      if (r.x * m0 >= thr) { int p = atomicAdd(s_cnt, 1); if (p < CAND_CAP) { cu[p] = __float_as_uint(r.x); cidx[p] = v0; } }
      if (r.y * m1 >= thr) { int p = atomicAdd(s_cnt, 1); if (p < CAND_CAP) { cu[p] = __float_as_uint(r.y); cidx[p] = v0 + 1; } }
      if (r.z * m2 >= thr) { int p = atomicAdd(s_cnt, 1); if (p < CAND_CAP) { cu[p] = __float_as_uint(r.z); cidx[p] = v0 + 2; } }
      if (r.w * m3 >= thr) { int p = atomicAdd(s_cnt, 1); if (p < CAND_CAP) { cu[p] = __float_as_uint(r.w); cidx[p] = v0 + 3; } }
    }
    if (tid < aoff + tailn) {
      int v = (tid < aoff) ? tid : (V_CONST - tailn) + (tid - aoff);
      float x = lrow[v];
      float m = ((mask[v >> 5] >> (v & 31)) & 1u) ? C_PEN : C_TEMP;
      if (x * m >= thr) { int p = atomicAdd(s_cnt, 1); if (p < CAND_CAP) { cu[p] = __float_as_uint(x); cidx[p] = v; } }
    }
    __syncthreads();
    const int tot = *s_cnt;
    n = (tot < CAND_CAP) ? tot : CAND_CAP;
    const bool window = (tot >= KTOP && tot <= CAND_CAP);
    const bool last = (attempt == 63);
    if (window || last) {
      if (n > 0) {
        for (int i = tid; i < n; i += NT) {
          float x = __uint_as_float(cu[i]);
          int v = cidx[i];
          float xe = x / 0.8f;
          if ((mask[v >> 5] >> (v & 31)) & 1u) xe = xe / 1.2f;
          cu[i] = f2u_desc(xe);
        }
        __syncthreads();
        rank_sort<NT>(n, cu, cidx, su, sidx, tid);
        __syncthreads();
      }
      if (window) {
        if (su[KTOP - 1] >= f2u_desc(thr) + 64u) break;
        if (last) break;
        thr = u2f(su[KTOP - 1] >= 96u ? su[KTOP - 1] - 96u : 0u);
      } else break;
    } else if (tot < KTOP) {
      uhi_ = f2u_desc(thr);
      if (attempt == 0) thr = 11.0f;
      else {
        uint32_t mid = ulo_ + (uhi_ - ulo_) / 2u;
        if (mid >= uhi_) mid = uhi_ - 1u;
        thr = u2f(mid);
      }
    } else {
      ulo_ = f2u_desc(thr);
      uint32_t mid = ulo_ + (uhi_ - ulo_) / 2u;
      if (mid <= ulo_) mid = ulo_ + 1u;
      thr = u2f(mid);
    }
  }
  return n;
}

// ---- shared tail: nsurv -> exp/gumbel -> top-p -> sample -> scatter ----
template<int NT>
__device__ void sample_tail(int n, uint32_t* su, int* sidx, float* eg, float* gg,
                            float* out, float* prow, int b, int B, int tid,
                            int* s_nsurv, int* s_ovf, int* s_rlast, float* s_z2) {
  if (tid < 64) {
    int n64 = (n < 64) ? n : 64;
    uint32_t sur = (tid < n64) ? su[tid] : 0u;
    int kpos = (n < KTOP) ? (n - 1) : (KTOP - 1);
    uint32_t kth = __shfl(sur, kpos, 64);
    unsigned long long m = __ballot(tid < n64 && sur == kth);
    int hi = 63 - __clzll(m);
    if (tid == 0) { *s_nsurv = hi + 1; *s_ovf = (hi == n64 - 1 && n > n64) ? 1 : 0; }
  }
  __syncthreads();
  const uint32_t half_total = (uint32_t)((size_t)B * V_CONST / 2);
  if (!(*s_ovf)) {
    // fast tail: wave-0 registers, op order identical to reference
    if (tid < 64) {
      const int nsurv = *s_nsurv;
      uint32_t sur = (tid < nsurv) ? su[tid] : 0u;
      int sidr = (tid < nsurv) ? sidx[tid] : 0x7FFFFFFF;
      float f = u2f(sur);
      float s0 = __shfl(f, 0, 64);
      float egr = 0.f, ggr = 0.f;
      if (tid < nsurv) {
        egr = expf(f - s0);
        ggr = gumbel_at((uint32_t)(b * V_CONST + sidr), half_total);
      }
      float scr = f + ggr;
      float zall = 0.f;
      for (int j = 0; j < nsurv; j++) zall += __shfl(egr, j, 64);
      float cum = 0.f, z2 = 0.f;
      int rlast = 0;
      float best = -3.402823466e38f; int besti = V_CONST;
      for (int j = 0; j < nsurv; j++) {
        float e = __shfl(egr, j, 64);
        cum += e / zall;
        if (j == 0 || cum <= 0.9f) {
          rlast = j; z2 += e;
          float sc = __shfl(scr, j, 64);
          int idx = __shfl(sidr, j, 64);
          if (sc > best || (sc == best && idx < besti)) { best = sc; besti = idx; }
        } else break;
      }
      if (tid == 0) out[b] = (float)besti;
      if (tid <= rlast && tid < nsurv) prow[sidr] = egr / z2;
    }
    return;
  }
  // serial fallback tail (nsurv > 64; never taken on this data)
  {
    const int nsurv = *s_nsurv;
    const float s0 = u2f(su[0]);
    for (int r = tid; r < nsurv; r += NT) {
      float f = u2f(su[r]);
      eg[r] = expf(f - s0);
      gg[r] = gumbel_at((uint32_t)(b * V_CONST + sidx[r]), half_total);
    }
    __syncthreads();
    if (tid == 0) {
      float zall = 0.f;
      for (int r = 0; r < nsurv; r++) zall += eg[r];
      float cum = 0.f; int rlast = 0;
      for (int r = 0; r < nsurv; r++) {
        cum += eg[r] / zall;
        if (r == 0 || cum <= 0.9f) rlast = r;
        else break;
      }
      float z2 = 0.f;
      for (int r = 0; r <= rlast; r++) z2 += eg[r];
      float best = -3.402823466e38f; int besti = V_CONST;
      for (int r = 0; r <= rlast; r++) {
        float sc = u2f(su[r]) + gg[r];
        int idx = sidx[r];
        if (sc > best || (sc == best && idx < besti)) { best = sc; besti = idx; }
      }
      out[b] = (float)besti;
      *s_rlast = rlast; *s_z2 = z2;
    }
    __syncthreads();
    const int rlast = *s_rlast;
    const float z2 = *s_z2;
    for (int r = tid; r <= rlast; r += NT) prow[sidx[r]] = eg[r] / z2;
  }
}

// ================= quad kernel: 4 blocks/row, 4th finisher samples ==========
#define QNT 256
__global__ __launch_bounds__(QNT) void quad_kernel(
    const float* __restrict__ logits, const int* __restrict__ generated,
    float* __restrict__ out, unsigned int* __restrict__ tickets,
    unsigned int* __restrict__ rowcnt, unsigned long long* __restrict__ pairs,
    int B, int T) {
  const int bid = blockIdx.x;
  const int b = bid >> 2, q = bid & 3;
  const int tid = threadIdx.x;
  const int vlo = q * Q4L;
  const int len = (q == 3) ? (V_CONST - 3 * Q4L) : Q4L;
  const int vhi = vlo + len;
  const int w0 = vlo >> 5;
  const int nw = ((vhi + 31) >> 5) - w0;

  __shared__ uint32_t mask[NMASK];   // quarter mask (offset w0); full in fallback
  __shared__ uint32_t cu[CAND_CAP];
  __shared__ int      cidx[CAND_CAP];
  __shared__ uint32_t su[CAND_CAP];
  __shared__ int      sidx[CAND_CAP];
  __shared__ int s_cnt, s_win, s_nsurv, s_ovf, s_rlast;
  __shared__ float s_z2;
  float* eg = (float*)cu;            // aliases: used only after cu/cidx are dead
  float* gg = (float*)cidx;

  for (int i = tid; i < nw; i += QNT) mask[i] = 0u;
  __syncthreads();

  // ---- quarter present-mask ----
  const int* grow = generated + (size_t)b * T;
  for (int i = tid; i < T; i += QNT) {
    int tok = grow[i];
    if (tok >= vlo && tok < vhi)
      atomicOr(&mask[(tok >> 5) - w0], 1u << (tok & 31));
  }
  __syncthreads();

  // ---- read-only screen of quarter; exact-key pairs -> global pool ----
  const float* lrow = logits + (size_t)b * V_CONST;
  float* prow = out + B + (size_t)b * V_CONST;
  const int aoff = (4 - (b & 3)) & 3;           // (b*V+vlo)%4 == b%4, vlo%4==0
  const int body4 = (len - aoff) >> 2;
  const int tailn = (len - aoff) & 3;
  const float4* arow4 = (const float4*)(lrow + vlo + aoff);
  unsigned long long* rowpairs = pairs + (size_t)b * CAND_CAP;

#define SCREEN1(xv, vv) do {                                              \
    int v_ = (vv); float x_ = (xv);                                       \
    if (x_ * C_TEMP >= THR_SCREEN) {                                      \
      uint32_t pres_ = (mask[(v_ >> 5) - w0] >> (v_ & 31)) & 1u;          \
      float xe_ = x_ / 0.8f; if (pres_) xe_ = xe_ / 1.2f;                 \
      unsigned int slot_ = atomicAdd(&rowcnt[b], 1u);                     \
      if (slot_ < CAND_CAP)                                               \
        atomicExch(&rowpairs[slot_],                                      \
                   ((unsigned long long)f2u_desc(xe_) << 32) | (uint32_t)v_); \
    } } while (0)

  for (int t = tid; t < body4; t += QNT) {
    float4 r = arow4[t];
    int v0 = vlo + aoff + (t << 2);
    SCREEN1(r.x, v0 + 0);
    SCREEN1(r.y, v0 + 1);
    SCREEN1(r.z, v0 + 2);
    SCREEN1(r.w, v0 + 3);
  }
  if (tid < aoff + tailn) {
    int v = (tid < aoff) ? (vlo + tid) : (vhi - tailn + (tid - aoff));
    SCREEN1(lrow[v], v);
  }
#undef SCREEN1

  // barrier drains the pair atomics (acked at the coherent point) before ticket
  __syncthreads();
  if (tid == 0) s_win = (atomicAdd(&tickets[b], 1u) == 3u) ? 1 : 0;
  __syncthreads();
  if (!s_win) return;

  // ================= winner: zero-fill row + gather + sort + tail ==========
  // zero-fill issued first; stores fly (L2-acked) under gather+sort
  {
    const int ftailn = (V_CONST - aoff) & 3;
    const int fbody4 = (V_CONST - aoff) >> 2;
    float4* orow4 = (float4*)(prow + aoff);
    const float4 z4 = make_float4(0.f, 0.f, 0.f, 0.f);
    for (int t = tid; t < fbody4; t += QNT) orow4[t] = z4;
    if (tid < aoff + ftailn) {
      int v = (tid < aoff) ? tid : (V_CONST - ftailn) + (tid - aoff);
      prow[v] = 0.f;
    }
  }

  if (tid == 0) s_cnt = (int)atomicAdd(&rowcnt[b], 0u);  // coherent read
  __syncthreads();
  const int total = s_cnt;
  int n = (total < CAND_CAP) ? total : CAND_CAP;
  bool ok = false;

  if (total >= KTOP && total <= CAND_CAP) {
    for (int i = tid; i < n; i += QNT) {
      unsigned long long pr = atomicAdd(&rowpairs[i], 0ull);  // coherent read
      cu[i] = (uint32_t)(pr >> 32);
      cidx[i] = (int)(uint32_t)pr;
    }
    __syncthreads();
    rank_sort<QNT>(n, cu, cidx, su, sidx, tid);
    __syncthreads();
    // certificate: non-passers have exact key < f2u(THR)+~4 ulp
    ok = (su[KTOP - 1] >= f2u_desc(THR_SCREEN) + 64u);
  }

  if (!ok) {
    // rebuild FULL row mask, then bisection rescan (L3-hot; never taken here)
    for (int i = tid; i < NMASK; i += QNT) mask[i] = 0u;
    __syncthreads();
    for (int i = tid; i < T; i += QNT) {
      int tok = grow[i];
      atomicOr(&mask[tok >> 5], 1u << (tok & 31));
    }
    const int ftailn = (V_CONST - aoff) & 3;
    const int fbody4 = (V_CONST - aoff) >> 2;
    n = rescan_bisect<QNT>(lrow, mask, aoff, fbody4, ftailn,
                           cu, cidx, su, sidx, &s_cnt, tid);
  }

  if (n == 0) { if (tid == 0) out[b] = 0.f; return; }
  // barriers inside sort/tail ordered the zero-fill before the scatter
  sample_tail<QNT>(n, su, sidx, eg, gg, out, prow, b, B, tid,
                   &s_nsurv, &s_ovf, &s_rlast, &s_z2);
}

// ================= mono kernel (R7, known-good) — ws-too-small path ==========
#define MNT 1024
__global__ __launch_bounds__(MNT) void mono_kernel(
    const float* __restrict__ logits, const int* __restrict__ generated,
    float* __restrict__ out, int B, int T) {
  const int b = blockIdx.x;
  const int tid = threadIdx.x;
  __shared__ uint32_t mask[NMASK];
  __shared__ uint32_t cu[CAND_CAP];
  __shared__ int      cidx[CAND_CAP];
  __shared__ uint32_t su[CAND_CAP];
  __shared__ int      sidx[CAND_CAP];
  __shared__ int s_cnt, s_nsurv, s_ovf, s_rlast;
  __shared__ float s_z2;
  float* eg = (float*)cu;
  float* gg = (float*)cidx;

  for (int i = tid; i < NMASK; i += MNT) mask[i] = 0u;
  if (tid == 0) s_cnt = 0;
  __syncthreads();
  const int* grow = generated + (size_t)b * T;
  for (int i = tid; i < T; i += MNT) {
    int tok = grow[i];
    atomicOr(&mask[tok >> 5], 1u << (tok & 31));
  }
  __syncthreads();

  const float* lrow = logits + (size_t)b * V_CONST;
  float* prow = out + B + (size_t)b * V_CONST;
  const int aoff = (4 - (b & 3)) & 3;
  const int tailn = (V_CONST - aoff) & 3;
  const int body4 = (V_CONST - aoff) >> 2;
  const float4* arow4 = (const float4*)(lrow + aoff);
  float4* orow4 = (float4*)(prow + aoff);
  const float4 z4 = make_float4(0.f, 0.f, 0.f, 0.f);

#define SCREEN1(xv, vv) do {                                          \
    int v_ = (vv); float x_ = (xv);                                   \
    if (x_ * C_TEMP >= THR_SCREEN) {                                  \
      uint32_t pres_ = (mask[v_ >> 5] >> (v_ & 31)) & 1u;             \
      float xe_ = x_ / 0.8f; if (pres_) xe_ = xe_ / 1.2f;             \
      int p_ = atomicAdd(&s_cnt, 1);                                  \
      if (p_ < CAND_CAP) { cu[p_] = f2u_desc(xe_); cidx[p_] = v_; }   \
    } } while (0)
  for (int t = tid; t < body4; t += MNT) {
    float4 r = arow4[t];
    orow4[t] = z4;
    int v0 = aoff + (t << 2);
    SCREEN1(r.x, v0 + 0);
    SCREEN1(r.y, v0 + 1);
    SCREEN1(r.z, v0 + 2);
    SCREEN1(r.w, v0 + 3);
  }
  if (tid < aoff + tailn) {
    int v = (tid < aoff) ? tid : (V_CONST - tailn) + (tid - aoff);
    prow[v] = 0.f;
    SCREEN1(lrow[v], v);
  }
#undef SCREEN1
  __syncthreads();

  const int total = s_cnt;
  int n = (total < CAND_CAP) ? total : CAND_CAP;
  bool ok = false;
  if (total >= KTOP && total <= CAND_CAP) {
    rank_sort<MNT>(n, cu, cidx, su, sidx, tid);
    __syncthreads();
    ok = (su[KTOP - 1] >= f2u_desc(THR_SCREEN) + 64u);
  } else {
    __syncthreads();
  }
  if (!ok) {
    n = rescan_bisect<MNT>(lrow, mask, aoff, body4, tailn,
                           cu, cidx, su, sidx, &s_cnt, tid);
  }
  if (n == 0) { if (tid == 0) out[b] = 0.f; return; }
  sample_tail<MNT>(n, su, sidx, eg, gg, out, prow, b, B, tid,
                   &s_nsurv, &s_ovf, &s_rlast, &s_z2);
}

extern "C" void kernel_launch(void* const* d_in, const int* in_sizes, int n_in,
                              void* d_out, int out_size, void* d_ws, size_t ws_size,
                              hipStream_t stream) {
  const float* logits = (const float*)d_in[0];
  const int* generated = (const int*)d_in[1];
  float* out = (float*)d_out;
  const int B = in_sizes[0] / V_CONST;
  const int T = in_sizes[1] / B;

  const size_t pairs_off = 8192;
  const size_t needed = pairs_off + (size_t)B * CAND_CAP * sizeof(unsigned long long);
  if (ws_size >= needed && B <= 1024) {
    unsigned int* tickets = (unsigned int*)d_ws;                   // [B]
    unsigned int* rowcnt = (unsigned int*)((char*)d_ws + 4096);    // [B]
    unsigned long long* pairs = (unsigned long long*)((char*)d_ws + pairs_off);
    hipMemsetAsync(d_ws, 0, 8192, stream);                         // reset tickets+rowcnt
    hipLaunchKernelGGL(quad_kernel, dim3(4 * B), dim3(QNT), 0, stream,
                       logits, generated, out, tickets, rowcnt, pairs, B, T);
  } else {
    hipLaunchKernelGGL(mono_kernel, dim3(B), dim3(MNT), 0, stream,
                       logits, generated, out, B, T);
  }
}

// Round 10
// 52.274 us; speedup vs baseline: 2.1533x; 2.1533x over previous
//
#include <hip/hip_runtime.h>
#include <stdint.h>

#define V_CONST 50257
#define NMASK ((V_CONST + 31) / 32)
#define KTOP 50
#define CAND_CAP 1024
#define NTHREADS 1024
#define THR_SCREEN 13.0f
#define C_TEMP 1.25f
#define C_PEN ((float)(1.25 / 1.2))
#define H0 25132   // half-split of the probs row (multiple of 4)
#define THREEFRY_PARTITIONABLE 1

__device__ __forceinline__ void tf_round(uint32_t &x0, uint32_t &x1, int r) {
  x0 += x1;
  x1 = (x1 << r) | (x1 >> (32 - r));
  x1 ^= x0;
}

// Threefry-2x32, 20 rounds, key = (0, 42)  [jax.random.key(42)]
__device__ __forceinline__ uint2 threefry_k_0_42(uint32_t x0, uint32_t x1) {
  const uint32_t ks0 = 0u;
  const uint32_t ks1 = 42u;
  const uint32_t ks2 = 0x1BD11BDAu ^ 0u ^ 42u;
  x0 += ks0; x1 += ks1;
  tf_round(x0, x1, 13); tf_round(x0, x1, 15); tf_round(x0, x1, 26); tf_round(x0, x1, 6);
  x0 += ks1; x1 += ks2 + 1u;
  tf_round(x0, x1, 17); tf_round(x0, x1, 29); tf_round(x0, x1, 16); tf_round(x0, x1, 24);
  x0 += ks2; x1 += ks0 + 2u;
  tf_round(x0, x1, 13); tf_round(x0, x1, 15); tf_round(x0, x1, 26); tf_round(x0, x1, 6);
  x0 += ks0; x1 += ks1 + 3u;
  tf_round(x0, x1, 17); tf_round(x0, x1, 29); tf_round(x0, x1, 16); tf_round(x0, x1, 24);
  x0 += ks1; x1 += ks2 + 4u;
  tf_round(x0, x1, 13); tf_round(x0, x1, 15); tf_round(x0, x1, 26); tf_round(x0, x1, 6);
  x0 += ks2; x1 += ks0 + 5u;
  uint2 r; r.x = x0; r.y = x1; return r;
}

__device__ __forceinline__ float gumbel_at(uint32_t p, uint32_t half_total) {
  uint32_t bits;
#if THREEFRY_PARTITIONABLE
  uint2 o = threefry_k_0_42(0u, p);
  bits = o.x ^ o.y;
#else
  if (p < half_total) {
    uint2 o = threefry_k_0_42(p, p + half_total);
    bits = o.x;
  } else {
    uint2 o = threefry_k_0_42(p - half_total, p);
    bits = o.y;
  }
#endif
  uint32_t ub = (bits >> 9) | 0x3F800000u;
  float u = __uint_as_float(ub) - 1.0f;
  u = u + 1.17549435e-38f;
  u = fmaxf(1.17549435e-38f, u);
  return -logf(-logf(u));
}

__device__ __forceinline__ uint32_t f2u_desc(float f) {
  uint32_t b = __float_as_uint(f);
  return (b & 0x80000000u) ? ~b : (b | 0x80000000u);
}
__device__ __forceinline__ float u2f(uint32_t u) {
  uint32_t b = (u & 0x80000000u) ? (u & 0x7FFFFFFFu) : ~u;
  return __uint_as_float(b);
}

// Twin-redundant mono kernel: blocks 2b and 2b+1 BOTH fully process row b.
// All global writes are idempotent (identical deterministic values), so no
// cross-block ordering is needed. Each block zero-fills only its half of the
// probs row; its own scatter follows its own zero-fill across vmcnt-draining
// barriers, so the last write to any address is always a scatter value.
__global__ __launch_bounds__(NTHREADS) void sample_kernel(
    const float* __restrict__ logits, const int* __restrict__ generated,
    float* __restrict__ out, int B, int T) {
  const int bid = blockIdx.x;
  const int b = bid >> 1, h = bid & 1;
  const int tid = threadIdx.x;

  __shared__ uint32_t mask[NMASK];
  __shared__ uint32_t cu[CAND_CAP];
  __shared__ int      cidx[CAND_CAP];
  __shared__ uint32_t su[CAND_CAP];
  __shared__ int      sidx[CAND_CAP];
  __shared__ int s_cnt, s_nsurv, s_ovf, s_rlast;
  __shared__ float s_z2;
  float* eg = (float*)cu;   // aliases: only used after cu/cidx are dead
  float* gg = (float*)cidx;

  // ---- LDS init (barrier is LDS-only: no global stores in flight yet) ----
  for (int i = tid; i < NMASK; i += NTHREADS) mask[i] = 0u;
  if (tid == 0) s_cnt = 0;
  __syncthreads();

  const float* lrow = logits + (size_t)b * V_CONST;
  float* prow = out + B + (size_t)b * V_CONST;

  // ---- issue zero-fill of MY half; stores drain under the screen stream ----
  {
    size_t base = (size_t)B + (size_t)b * V_CONST;
    size_t e0 = base + (h ? H0 : 0);
    size_t e1 = base + (h ? V_CONST : H0);
    size_t a0 = (e0 + 3) & ~(size_t)3;
    size_t a1 = e1 & ~(size_t)3;
    for (size_t e = e0 + tid; e < a0; e += NTHREADS) out[e] = 0.f;
    float4* o4 = (float4*)(out + a0);
    size_t n4 = (a1 - a0) >> 2;
    const float4 z4 = make_float4(0.f, 0.f, 0.f, 0.f);
    for (size_t i = tid; i < n4; i += NTHREADS) o4[i] = z4;
    for (size_t e = a1 + tid; e < e1; e += NTHREADS) out[e] = 0.f;
  }

  // ---- prefetch generated tokens into registers (mask built after screen) ----
  const int* grow = generated + (size_t)b * T;
  int toks[4];
  int ntok = 0;
  for (int i = tid; i < T && ntok < 4; i += NTHREADS) toks[ntok++] = grow[i];

  // ---- mask-free read-only screen of the FULL row (2-deep pipelined) ----
  const int aoff = (4 - (b & 3)) & 3;
  const int tailn = (V_CONST - aoff) & 3;
  const int body4 = (V_CONST - aoff) >> 2;
  const float4* arow4 = (const float4*)(lrow + aoff);

#define PUSH_RAW(xv, vv) do {                                          \
    int p_ = atomicAdd(&s_cnt, 1);                                     \
    if (p_ < CAND_CAP) { cu[p_] = __float_as_uint(xv); cidx[p_] = (vv); } \
  } while (0)

  {
    int t = tid;
    bool has = (t < body4);
    float4 rc;
    if (has) rc = arow4[t];
    while (has) {
      int t2 = t + NTHREADS;
      bool has2 = (t2 < body4);
      float4 rn;
      if (has2) rn = arow4[t2];        // next load in flight over processing
      int v0 = aoff + (t << 2);
      if (rc.x * C_TEMP >= THR_SCREEN) PUSH_RAW(rc.x, v0 + 0);
      if (rc.y * C_TEMP >= THR_SCREEN) PUSH_RAW(rc.y, v0 + 1);
      if (rc.z * C_TEMP >= THR_SCREEN) PUSH_RAW(rc.z, v0 + 2);
      if (rc.w * C_TEMP >= THR_SCREEN) PUSH_RAW(rc.w, v0 + 3);
      t = t2; rc = rn; has = has2;
    }
    if (tid < aoff + tailn) {
      int v = (tid < aoff) ? tid : (V_CONST - tailn) + (tid - aoff);
      float x = lrow[v];
      if (x * C_TEMP >= THR_SCREEN) PUSH_RAW(x, v);
    }
  }
#undef PUSH_RAW

  // ---- build present mask (prefetched regs + leftovers) ----
  for (int k = 0; k < ntok; k++) {
    int tok = toks[k];
    atomicOr(&mask[tok >> 5], 1u << (tok & 31));
  }
  for (int i = tid + 4 * NTHREADS; i < T; i += NTHREADS) {
    int tok = grow[i];
    atomicOr(&mask[tok >> 5], 1u << (tok & 31));
  }
  __syncthreads();   // zero-fill stores long since overlapped by the screen

  const int total = s_cnt;
  int n = (total < CAND_CAP) ? total : CAND_CAP;
  bool ok = false;

  if (total >= KTOP && total <= CAND_CAP) {
    // exact keys (true IEEE divisions) for candidates only
    for (int i = tid; i < n; i += NTHREADS) {
      float x = __uint_as_float(cu[i]);
      int v = cidx[i];
      float xe = x / 0.8f;
      if ((mask[v >> 5] >> (v & 31)) & 1u) xe = xe / 1.2f;
      cu[i] = f2u_desc(xe);
    }
    __syncthreads();
    // stable rank sort (descending, ties by smaller index)
    for (int i = tid; i < n; i += NTHREADS) {
      uint32_t ui = cu[i]; int ii = cidx[i];
      int rank = 0;
      for (int j = 0; j < n; j++) {
        uint32_t uj = cu[j];
        rank += ((uj > ui) || (uj == ui && cidx[j] < ii)) ? 1 : 0;
      }
      su[rank] = ui; sidx[rank] = ii;
    }
    __syncthreads();
    // certificate: non-candidates have exact key < f2u(THR)+~4 ulp
    ok = (su[KTOP - 1] >= f2u_desc(THR_SCREEN) + 64u);
  }

  if (!ok) {
    // ---- robust fallback: mask-aware bisection rescan (never taken here) ----
    float thr = THR_SCREEN;
    uint32_t ulo_ = 0u, uhi_ = 0xFFFFFFFFu;
    n = 0;
    for (int attempt = 0; attempt < 64; ++attempt) {
      __syncthreads();
      if (tid == 0) s_cnt = 0;
      __syncthreads();
      for (int t = tid; t < body4; t += NTHREADS) {
        float4 r = arow4[t];
        int v0 = aoff + (t << 2);
        uint32_t w = (mask[v0 >> 5] >> (v0 & 31)) & 0xFu;
        float m0 = (w & 1u) ? C_PEN : C_TEMP;
        float m1 = (w & 2u) ? C_PEN : C_TEMP;
        float m2 = (w & 4u) ? C_PEN : C_TEMP;
        float m3 = (w & 8u) ? C_PEN : C_TEMP;
        if (r.x * m0 >= thr) { int p = atomicAdd(&s_cnt, 1); if (p < CAND_CAP) { cu[p] = __float_as_uint(r.x); cidx[p] = v0; } }
        if (r.y * m1 >= thr) { int p = atomicAdd(&s_cnt, 1); if (p < CAND_CAP) { cu[p] = __float_as_uint(r.y); cidx[p] = v0 + 1; } }
        if (r.z * m2 >= thr) { int p = atomicAdd(&s_cnt, 1); if (p < CAND_CAP) { cu[p] = __float_as_uint(r.z); cidx[p] = v0 + 2; } }
        if (r.w * m3 >= thr) { int p = atomicAdd(&s_cnt, 1); if (p < CAND_CAP) { cu[p] = __float_as_uint(r.w); cidx[p] = v0 + 3; } }
      }
      if (tid < aoff + tailn) {
        int v = (tid < aoff) ? tid : (V_CONST - tailn) + (tid - aoff);
        float x = lrow[v];
        float m = ((mask[v >> 5] >> (v & 31)) & 1u) ? C_PEN : C_TEMP;
        if (x * m >= thr) { int p = atomicAdd(&s_cnt, 1); if (p < CAND_CAP) { cu[p] = __float_as_uint(x); cidx[p] = v; } }
      }
      __syncthreads();
      const int tot = s_cnt;
      n = (tot < CAND_CAP) ? tot : CAND_CAP;
      const bool window = (tot >= KTOP && tot <= CAND_CAP);
      const bool last = (attempt == 63);
      if (window || last) {
        if (n > 0) {
          for (int i = tid; i < n; i += NTHREADS) {
            float x = __uint_as_float(cu[i]);
            int v = cidx[i];
            float xe = x / 0.8f;
            if ((mask[v >> 5] >> (v & 31)) & 1u) xe = xe / 1.2f;
            cu[i] = f2u_desc(xe);
          }
          __syncthreads();
          for (int i = tid; i < n; i += NTHREADS) {
            uint32_t ui = cu[i]; int ii = cidx[i];
            int rank = 0;
            for (int j = 0; j < n; j++) {
              uint32_t uj = cu[j];
              rank += ((uj > ui) || (uj == ui && cidx[j] < ii)) ? 1 : 0;
            }
            su[rank] = ui; sidx[rank] = ii;
          }
          __syncthreads();
        }
        if (window) {
          if (su[KTOP - 1] >= f2u_desc(thr) + 64u) break;
          if (last) break;
          thr = u2f(su[KTOP - 1] >= 96u ? su[KTOP - 1] - 96u : 0u);
        } else break;
      } else if (tot < KTOP) {
        uhi_ = f2u_desc(thr);
        if (attempt == 0) thr = 11.0f;
        else {
          uint32_t mid = ulo_ + (uhi_ - ulo_) / 2u;
          if (mid >= uhi_) mid = uhi_ - 1u;
          thr = u2f(mid);
        }
      } else {
        ulo_ = f2u_desc(thr);
        uint32_t mid = ulo_ + (uhi_ - ulo_) / 2u;
        if (mid <= ulo_) mid = ulo_ + 1u;
        thr = u2f(mid);
      }
    }
  }

  if (n == 0) { if (tid == 0) out[b] = 0.f; return; }

  // ---- nsurv via wave 0 (ballot); overflow -> serial fallback tail ----
  if (tid < 64) {
    int n64 = (n < 64) ? n : 64;
    uint32_t sur = (tid < n64) ? su[tid] : 0u;
    int kpos = (n < KTOP) ? (n - 1) : (KTOP - 1);
    uint32_t kth = __shfl(sur, kpos, 64);
    unsigned long long m = __ballot(tid < n64 && sur == kth);
    int hi = 63 - __clzll(m);
    if (tid == 0) {
      s_nsurv = hi + 1;
      s_ovf = (hi == n64 - 1 && n > n64) ? 1 : 0;
    }
  }
  __syncthreads();

  const uint32_t half_total = (uint32_t)((size_t)B * V_CONST / 2);

  if (!s_ovf) {
    // fast tail: wave-0 registers, op order identical to reference
    if (tid < 64) {
      const int nsurv = s_nsurv;
      uint32_t sur = (tid < nsurv) ? su[tid] : 0u;
      int sidr = (tid < nsurv) ? sidx[tid] : 0x7FFFFFFF;
      float f = u2f(sur);
      float s0 = __shfl(f, 0, 64);
      float egr = 0.f, ggr = 0.f;
      if (tid < nsurv) {
        egr = expf(f - s0);
        ggr = gumbel_at((uint32_t)(b * V_CONST + sidr), half_total);
      }
      float scr = f + ggr;
      float zall = 0.f;
      for (int j = 0; j < nsurv; j++) zall += __shfl(egr, j, 64);
      float cum = 0.f, z2 = 0.f;
      int rlast = 0;
      float best = -3.402823466e38f; int besti = V_CONST;
      for (int j = 0; j < nsurv; j++) {
        float e = __shfl(egr, j, 64);
        cum += e / zall;
        if (j == 0 || cum <= 0.9f) {
          rlast = j; z2 += e;
          float sc = __shfl(scr, j, 64);
          int idx = __shfl(sidr, j, 64);
          if (sc > best || (sc == best && idx < besti)) { best = sc; besti = idx; }
        } else break;
      }
      if (tid == 0) out[b] = (float)besti;
      if (tid <= rlast && tid < nsurv) prow[sidr] = egr / z2;
    }
    return;
  }

  // serial fallback tail (nsurv > 64; never taken on this data)
  {
    const int nsurv = s_nsurv;
    const float s0 = u2f(su[0]);
    for (int r = tid; r < nsurv; r += NTHREADS) {
      float f = u2f(su[r]);
      eg[r] = expf(f - s0);
      gg[r] = gumbel_at((uint32_t)(b * V_CONST + sidx[r]), half_total);
    }
    __syncthreads();
    if (tid == 0) {
      float zall = 0.f;
      for (int r = 0; r < nsurv; r++) zall += eg[r];
      float cum = 0.f; int rlast = 0;
      for (int r = 0; r < nsurv; r++) {
        cum += eg[r] / zall;
        if (r == 0 || cum <= 0.9f) rlast = r;
        else break;
      }
      float z2 = 0.f;
      for (int r = 0; r <= rlast; r++) z2 += eg[r];
      float best = -3.402823466e38f; int besti = V_CONST;
      for (int r = 0; r <= rlast; r++) {
        float sc = u2f(su[r]) + gg[r];
        int idx = sidx[r];
        if (sc > best || (sc == best && idx < besti)) { best = sc; besti = idx; }
      }
      out[b] = (float)besti;
      s_rlast = rlast; s_z2 = z2;
    }
    __syncthreads();
    const int rlast = s_rlast;
    const float z2 = s_z2;
    for (int r = tid; r <= rlast; r += NTHREADS) prow[sidx[r]] = eg[r] / z2;
  }
}

extern "C" void kernel_launch(void* const* d_in, const int* in_sizes, int n_in,
                              void* d_out, int out_size, void* d_ws, size_t ws_size,
                              hipStream_t stream) {
  const float* logits = (const float*)d_in[0];
  const int* generated = (const int*)d_in[1];
  float* out = (float*)d_out;
  const int B = in_sizes[0] / V_CONST;
  const int T = in_sizes[1] / B;
  hipLaunchKernelGGL(sample_kernel, dim3(2 * B), dim3(NTHREADS), 0, stream,
                     logits, generated, out, B, T);
}

// Round 12
// 33.857 us; speedup vs baseline: 3.3246x; 1.5440x over previous
//
#include <hip/hip_runtime.h>
#include <stdint.h>

#define V_CONST 50257
#define NMASK ((V_CONST + 31) / 32)
#define KTOP 50
#define CAND_CAP 1024
#define NTHREADS 1024
#define THR_SCREEN 13.0f
#define C_TEMP 1.25f
#define C_PEN ((float)(1.25 / 1.2))
#define THREEFRY_PARTITIONABLE 1

typedef float f32x4 __attribute__((ext_vector_type(4)));

__device__ __forceinline__ void tf_round(uint32_t &x0, uint32_t &x1, int r) {
  x0 += x1;
  x1 = (x1 << r) | (x1 >> (32 - r));
  x1 ^= x0;
}

// Threefry-2x32, 20 rounds, key = (0, 42)  [jax.random.key(42)]
__device__ __forceinline__ uint2 threefry_k_0_42(uint32_t x0, uint32_t x1) {
  const uint32_t ks0 = 0u;
  const uint32_t ks1 = 42u;
  const uint32_t ks2 = 0x1BD11BDAu ^ 0u ^ 42u;
  x0 += ks0; x1 += ks1;
  tf_round(x0, x1, 13); tf_round(x0, x1, 15); tf_round(x0, x1, 26); tf_round(x0, x1, 6);
  x0 += ks1; x1 += ks2 + 1u;
  tf_round(x0, x1, 17); tf_round(x0, x1, 29); tf_round(x0, x1, 16); tf_round(x0, x1, 24);
  x0 += ks2; x1 += ks0 + 2u;
  tf_round(x0, x1, 13); tf_round(x0, x1, 15); tf_round(x0, x1, 26); tf_round(x0, x1, 6);
  x0 += ks0; x1 += ks1 + 3u;
  tf_round(x0, x1, 17); tf_round(x0, x1, 29); tf_round(x0, x1, 16); tf_round(x0, x1, 24);
  x0 += ks1; x1 += ks2 + 4u;
  tf_round(x0, x1, 13); tf_round(x0, x1, 15); tf_round(x0, x1, 26); tf_round(x0, x1, 6);
  x0 += ks2; x1 += ks0 + 5u;
  uint2 r; r.x = x0; r.y = x1; return r;
}

__device__ __forceinline__ float gumbel_at(uint32_t p, uint32_t half_total) {
  uint32_t bits;
#if THREEFRY_PARTITIONABLE
  uint2 o = threefry_k_0_42(0u, p);
  bits = o.x ^ o.y;
#else
  if (p < half_total) {
    uint2 o = threefry_k_0_42(p, p + half_total);
    bits = o.x;
  } else {
    uint2 o = threefry_k_0_42(p - half_total, p);
    bits = o.y;
  }
#endif
  uint32_t ub = (bits >> 9) | 0x3F800000u;
  float u = __uint_as_float(ub) - 1.0f;
  u = u + 1.17549435e-38f;
  u = fmaxf(1.17549435e-38f, u);
  return -logf(-logf(u));
}

__device__ __forceinline__ uint32_t f2u_desc(float f) {
  uint32_t b = __float_as_uint(f);
  return (b & 0x80000000u) ? ~b : (b | 0x80000000u);
}
__device__ __forceinline__ float u2f(uint32_t u) {
  uint32_t b = (u & 0x80000000u) ? (u & 0x7FFFFFFFu) : ~u;
  return __uint_as_float(b);
}

__global__ __launch_bounds__(NTHREADS) void sample_kernel(
    const float* __restrict__ logits, const int* __restrict__ generated,
    float* __restrict__ out, int B, int T) {
  const int b = blockIdx.x;
  const int tid = threadIdx.x;

  __shared__ uint32_t mask[NMASK];
  __shared__ uint32_t cu[CAND_CAP];
  __shared__ int      cidx[CAND_CAP];
  __shared__ uint32_t su[CAND_CAP];
  __shared__ int      sidx[CAND_CAP];
  __shared__ int s_cnt, s_nsurv, s_ovf, s_rlast;
  __shared__ float s_z2;
  float* eg = (float*)cu;   // aliases: only used after cu/cidx are dead
  float* gg = (float*)cidx;

  // ---- A: present-token bitmask (LDS only; barriers are cheap) ----
  for (int i = tid; i < NMASK; i += NTHREADS) mask[i] = 0u;
  if (tid == 0) s_cnt = 0;
  __syncthreads();
  const int* grow = generated + (size_t)b * T;
  for (int i = tid; i < T; i += NTHREADS) {
    int tok = grow[i];
    atomicOr(&mask[tok >> 5], 1u << (tok & 31));
  }
  __syncthreads();

  // ---- B: fused screen (exact keys) + NT zero-fill of probs row ----
  const float* lrow = logits + (size_t)b * V_CONST;
  float* prow = out + B + (size_t)b * V_CONST;
  const int aoff = (4 - (b & 3)) & 3;
  const int tailn = (V_CONST - aoff) & 3;
  const int body4 = (V_CONST - aoff) >> 2;
  const float4* arow4 = (const float4*)(lrow + aoff);
  f32x4* orow4 = (f32x4*)(prow + aoff);
  const f32x4 z4 = {0.f, 0.f, 0.f, 0.f};

#define SCREEN1(xv, vv) do {                                          \
    int v_ = (vv); float x_ = (xv);                                   \
    uint32_t pres_ = (mask[v_ >> 5] >> (v_ & 31)) & 1u;               \
    float m_ = pres_ ? C_PEN : C_TEMP;                                \
    if (x_ * m_ >= THR_SCREEN) {                                      \
      float xe_ = x_ / 0.8f; if (pres_) xe_ = xe_ / 1.2f;             \
      int p_ = atomicAdd(&s_cnt, 1);                                  \
      if (p_ < CAND_CAP) { cu[p_] = f2u_desc(xe_); cidx[p_] = v_; }   \
    } } while (0)

  for (int t = tid; t < body4; t += NTHREADS) {
    float4 r = arow4[t];
    __builtin_nontemporal_store(z4, &orow4[t]);  // NT: don't pollute L2/L3
    int v0 = aoff + (t << 2);
    SCREEN1(r.x, v0 + 0);
    SCREEN1(r.y, v0 + 1);
    SCREEN1(r.z, v0 + 2);
    SCREEN1(r.w, v0 + 3);
  }
  if (tid < aoff + tailn) {
    int v = (tid < aoff) ? tid : (V_CONST - tailn) + (tid - aoff);
    __builtin_nontemporal_store(0.f, &prow[v]);
    float x = lrow[v];
    SCREEN1(x, v);
  }
#undef SCREEN1
  __syncthreads();   // vmcnt(0) drain orders NT zeros before any scatter

  const int total = s_cnt;
  int n = (total < CAND_CAP) ? total : CAND_CAP;
  bool ok = false;

  if (total >= KTOP && total <= CAND_CAP) {
    // ---- C: stable rank sort (descending, ties by smaller index) ----
    for (int i = tid; i < n; i += NTHREADS) {
      uint32_t ui = cu[i]; int ii = cidx[i];
      int rank = 0;
      for (int j = 0; j < n; j++) {
        uint32_t uj = cu[j];
        rank += ((uj > ui) || (uj == ui && cidx[j] < ii)) ? 1 : 0;
      }
      su[rank] = ui; sidx[rank] = ii;
    }
    __syncthreads();
    // certificate: non-passers have exact key < f2u(THR)+~4 ulp
    ok = (su[KTOP - 1] >= f2u_desc(THR_SCREEN) + 64u);
  } else {
    __syncthreads();
  }

  if (!ok) {
    // ---- robust fallback: bisection re-scan (never taken on this data) ----
    float thr = THR_SCREEN;
    uint32_t ulo_ = 0u, uhi_ = 0xFFFFFFFFu;
    n = 0;
    for (int attempt = 0; attempt < 64; ++attempt) {
      __syncthreads();
      if (tid == 0) s_cnt = 0;
      __syncthreads();
      for (int t = tid; t < body4; t += NTHREADS) {
        float4 r = arow4[t];
        int v0 = aoff + (t << 2);
        uint32_t w = (mask[v0 >> 5] >> (v0 & 31)) & 0xFu;
        float m0 = (w & 1u) ? C_PEN : C_TEMP;
        float m1 = (w & 2u) ? C_PEN : C_TEMP;
        float m2 = (w & 4u) ? C_PEN : C_TEMP;
        float m3 = (w & 8u) ? C_PEN : C_TEMP;
        if (r.x * m0 >= thr) { int p = atomicAdd(&s_cnt, 1); if (p < CAND_CAP) { cu[p] = __float_as_uint(r.x); cidx[p] = v0; } }
        if (r.y * m1 >= thr) { int p = atomicAdd(&s_cnt, 1); if (p < CAND_CAP) { cu[p] = __float_as_uint(r.y); cidx[p] = v0 + 1; } }
        if (r.z * m2 >= thr) { int p = atomicAdd(&s_cnt, 1); if (p < CAND_CAP) { cu[p] = __float_as_uint(r.z); cidx[p] = v0 + 2; } }
        if (r.w * m3 >= thr) { int p = atomicAdd(&s_cnt, 1); if (p < CAND_CAP) { cu[p] = __float_as_uint(r.w); cidx[p] = v0 + 3; } }
      }
      if (tid < aoff + tailn) {
        int v = (tid < aoff) ? tid : (V_CONST - tailn) + (tid - aoff);
        float x = lrow[v];
        float m = ((mask[v >> 5] >> (v & 31)) & 1u) ? C_PEN : C_TEMP;
        if (x * m >= thr) { int p = atomicAdd(&s_cnt, 1); if (p < CAND_CAP) { cu[p] = __float_as_uint(x); cidx[p] = v; } }
      }
      __syncthreads();
      const int tot = s_cnt;
      n = (tot < CAND_CAP) ? tot : CAND_CAP;
      const bool window = (tot >= KTOP && tot <= CAND_CAP);
      const bool last = (attempt == 63);
      if (window || last) {
        if (n > 0) {
          for (int i = tid; i < n; i += NTHREADS) {
            float x = __uint_as_float(cu[i]);
            int v = cidx[i];
            float xe = x / 0.8f;
            if ((mask[v >> 5] >> (v & 31)) & 1u) xe = xe / 1.2f;
            cu[i] = f2u_desc(xe);
          }
          __syncthreads();
          for (int i = tid; i < n; i += NTHREADS) {
            uint32_t ui = cu[i]; int ii = cidx[i];
            int rank = 0;
            for (int j = 0; j < n; j++) {
              uint32_t uj = cu[j];
              rank += ((uj > ui) || (uj == ui && cidx[j] < ii)) ? 1 : 0;
            }
            su[rank] = ui; sidx[rank] = ii;
          }
          __syncthreads();
        }
        if (window) {
          if (su[KTOP - 1] >= f2u_desc(thr) + 64u) break;
          if (last) break;
          thr = u2f(su[KTOP - 1] >= 96u ? su[KTOP - 1] - 96u : 0u);
        } else break;
      } else if (tot < KTOP) {
        uhi_ = f2u_desc(thr);
        if (attempt == 0) thr = 11.0f;
        else {
          uint32_t mid = ulo_ + (uhi_ - ulo_) / 2u;
          if (mid >= uhi_) mid = uhi_ - 1u;
          thr = u2f(mid);
        }
      } else {
        ulo_ = f2u_desc(thr);
        uint32_t mid = ulo_ + (uhi_ - ulo_) / 2u;
        if (mid <= ulo_) mid = ulo_ + 1u;
        thr = u2f(mid);
      }
    }
  }

  if (n == 0) { if (tid == 0) out[b] = 0.f; return; }

  // ---- nsurv via wave 0 (ballot); overflow -> serial fallback tail ----
  if (tid < 64) {
    int n64 = (n < 64) ? n : 64;
    uint32_t sur = (tid < n64) ? su[tid] : 0u;
    int kpos = (n < KTOP) ? (n - 1) : (KTOP - 1);
    uint32_t kth = __shfl(sur, kpos, 64);
    unsigned long long m = __ballot(tid < n64 && sur == kth);
    int hi = 63 - __clzll(m);
    if (tid == 0) {
      s_nsurv = hi + 1;
      s_ovf = (hi == n64 - 1 && n > n64) ? 1 : 0;
    }
  }
  __syncthreads();

  const uint32_t half_total = (uint32_t)((size_t)B * V_CONST / 2);

  if (!s_ovf) {
    // fast tail: wave-0 registers, op order identical to reference
    if (tid < 64) {
      const int nsurv = s_nsurv;
      uint32_t sur = (tid < nsurv) ? su[tid] : 0u;
      int sidr = (tid < nsurv) ? sidx[tid] : 0x7FFFFFFF;
      float f = u2f(sur);
      float s0 = __shfl(f, 0, 64);
      float egr = 0.f, ggr = 0.f;
      if (tid < nsurv) {
        egr = expf(f - s0);
        ggr = gumbel_at((uint32_t)(b * V_CONST + sidr), half_total);
      }
      float scr = f + ggr;
      float zall = 0.f;
      for (int j = 0; j < nsurv; j++) zall += __shfl(egr, j, 64);
      float cum = 0.f, z2 = 0.f;
      int rlast = 0;
      float best = -3.402823466e38f; int besti = V_CONST;
      for (int j = 0; j < nsurv; j++) {
        float e = __shfl(egr, j, 64);
        cum += e / zall;
        if (j == 0 || cum <= 0.9f) {
          rlast = j; z2 += e;
          float sc = __shfl(scr, j, 64);
          int idx = __shfl(sidr, j, 64);
          if (sc > best || (sc == best && idx < besti)) { best = sc; besti = idx; }
        } else break;
      }
      if (tid == 0) out[b] = (float)besti;
      if (tid <= rlast && tid < nsurv) prow[sidr] = egr / z2;
    }
    return;
  }

  // serial fallback tail (nsurv > 64; never taken on this data)
  {
    const int nsurv = s_nsurv;
    const float s0 = u2f(su[0]);
    for (int r = tid; r < nsurv; r += NTHREADS) {
      float f = u2f(su[r]);
      eg[r] = expf(f - s0);
      gg[r] = gumbel_at((uint32_t)(b * V_CONST + sidx[r]), half_total);
    }
    __syncthreads();
    if (tid == 0) {
      float zall = 0.f;
      for (int r = 0; r < nsurv; r++) zall += eg[r];
      float cum = 0.f; int rlast = 0;
      for (int r = 0; r < nsurv; r++) {
        cum += eg[r] / zall;
        if (r == 0 || cum <= 0.9f) rlast = r;
        else break;
      }
      float z2 = 0.f;
      for (int r = 0; r <= rlast; r++) z2 += eg[r];
      float best = -3.402823466e38f; int besti = V_CONST;
      for (int r = 0; r <= rlast; r++) {
        float sc = u2f(su[r]) + gg[r];
        int idx = sidx[r];
        if (sc > best || (sc == best && idx < besti)) { best = sc; besti = idx; }
      }
      out[b] = (float)besti;
      s_rlast = rlast; s_z2 = z2;
    }
    __syncthreads();
    const int rlast = s_rlast;
    const float z2 = s_z2;
    for (int r = tid; r <= rlast; r += NTHREADS) prow[sidx[r]] = eg[r] / z2;
  }
}

extern "C" void kernel_launch(void* const* d_in, const int* in_sizes, int n_in,
                              void* d_out, int out_size, void* d_ws, size_t ws_size,
                              hipStream_t stream) {
  const float* logits = (const float*)d_in[0];
  const int* generated = (const int*)d_in[1];
  float* out = (float*)d_out;
  const int B = in_sizes[0] / V_CONST;
  const int T = in_sizes[1] / B;
  hipLaunchKernelGGL(sample_kernel, dim3(B), dim3(NTHREADS), 0, stream,
                     logits, generated, out, B, T);
}